// Round 14
// baseline (214.564 us; speedup 1.0000x reference)
//
#include <hip/hip_runtime.h>
#include <hip/hip_bf16.h>

#define NN 8192
#define EE 262144
#define DD 256
#define FF 512
#define MM 256

typedef __attribute__((ext_vector_type(8))) short short8v;
typedef __attribute__((ext_vector_type(16))) float float16v;

__device__ __forceinline__ ushort f2bf(float x) {
  union { float f; unsigned u; } c; c.f = x;
  unsigned r = (c.u + 0x7FFF + ((c.u >> 16) & 1)) >> 16;
  return (ushort)r;
}
__device__ __forceinline__ float b2f(ushort u) {
  union { unsigned u; float f; } c; c.u = ((unsigned)u) << 16;
  return c.f;
}
__device__ __forceinline__ void async_copy16(void* lds, const void* g) {
  __builtin_amdgcn_global_load_lds(
      (const __attribute__((address_space(1))) void*)g,
      (__attribute__((address_space(3))) void*)lds, 16, 0, 0);
}

// ---------------- CSR scan / fill ----------------
__global__ __launch_bounds__(1024) void scan_kernel(const int* __restrict__ degi,
                                                    int* __restrict__ csr_off,
                                                    float* __restrict__ dinv) {
  __shared__ int part[1024];
  int tid = threadIdx.x;
  int base = tid * 8;
  int loc[8], dv[8]; int s = 0;
#pragma unroll
  for (int i = 0; i < 8; ++i) { int d = degi[base + i]; dv[i] = d; loc[i] = s; s += d; }
  part[tid] = s;
  __syncthreads();
  for (int off = 1; off < 1024; off <<= 1) {
    int v = (tid >= off) ? part[tid - off] : 0;
    __syncthreads();
    part[tid] += v;
    __syncthreads();
  }
  int pre = (tid == 0) ? 0 : part[tid - 1];
#pragma unroll
  for (int i = 0; i < 8; ++i) {
    csr_off[base + i] = pre + loc[i];
    dinv[base + i] = rsqrtf((float)(dv[i] + 1));  // +1 self loop
  }
  if (tid == 1023) csr_off[NN] = part[1023];
}

__global__ void fill_kernel(const int* __restrict__ ei, const int* __restrict__ csr_off,
                            int* __restrict__ cursor, int* __restrict__ csr_src) {
  int i = blockIdx.x * blockDim.x + threadIdx.x;
  if (i < EE) {
    int d = ei[EE + i];
    int pos = csr_off[d] + atomicAdd(&cursor[d], 1);
    csr_src[pos] = ei[i];
  }
}

// ---------------- fused precompute: converts + bias folds + edge COUNT ----------------
#define QSCALE 0.090168441f   // log2(e) / 16
#define P1B 10753             // ceil(2752768 / 256)
__global__ __launch_bounds__(256) void prep_kernel(
    const float* __restrict__ h, const float* __restrict__ W_gcn,
    const float* __restrict__ Wv, const float* __restrict__ Wo,
    const float* __restrict__ W1, const float* __restrict__ W2,
    const float* __restrict__ bv,
    const float* __restrict__ Wq, const float* __restrict__ Wk,
    const float* __restrict__ bq, const float* __restrict__ bk,
    const float* __restrict__ RF, const int* __restrict__ ei,
    ushort* __restrict__ hb, ushort* __restrict__ WgcnT, ushort* __restrict__ Wcat,
    ushort* __restrict__ WoT, ushort* __restrict__ W1T, ushort* __restrict__ W2T,
    ushort* __restrict__ RFb, ushort* __restrict__ Wqkb,
    float* __restrict__ bcat, int* __restrict__ degi)
{
  if (blockIdx.x < P1B) {
    int i = blockIdx.x * 256 + threadIdx.x;
    const int R0 = NN * DD;
    const int R1 = R0 + DD * DD;
    const int R2 = R1 + DD * DD;
    const int R3 = R2 + DD * DD;
    const int R4 = R3 + DD * FF;
    const int R5 = R4 + FF * DD;
    const int R6 = R5 + DD;
    const int R7 = R6 + DD * DD;
    const int R8 = R7 + DD * DD;
    const int R9 = R8 + DD * DD;
    if (i < R0) {
      hb[i] = f2bf(h[i]);
    } else if (i < R1) {
      int j = i - R0; int n = j >> 8, k = j & 255;
      WgcnT[(n << 8) | k] = f2bf(W_gcn[k * DD + n]);
    } else if (i < R2) {
      int j = i - R1; int n = j >> 8, k = j & 255;
      Wcat[((512 + n) << 8) | k] = f2bf(Wv[k * DD + n]);
    } else if (i < R3) {
      int j = i - R2; int n = j >> 8, k = j & 255;
      WoT[(n << 8) | k] = f2bf(Wo[k * DD + n]);
    } else if (i < R4) {
      int j = i - R3; int n = j >> 8, k = j & 255;
      W1T[(n << 8) | k] = f2bf(W1[k * FF + n]);
    } else if (i < R5) {
      int j = i - R4; int n = j >> 9, k = j & 511;
      W2T[n * FF + k] = f2bf(W2[k * DD + n]);
    } else if (i < R6) {
      bcat[512 + (i - R5)] = bv[i - R5];
    } else if (i < R7) {
      int j = i - R6;
      RFb[j] = f2bf(RF[j]);                       // RF [m][t] plain
    } else if (i < R8) {
      int j = i - R7;
      Wqkb[j] = f2bf(Wq[j] * QSCALE);             // rows 0-255: Wq [d][t] scaled
    } else if (i < R9) {
      int j = i - R8;
      Wqkb[DD * DD + j] = f2bf(Wk[j]);            // rows 256-511: Wk [d][t]
    }
  } else if (blockIdx.x < P1B + 2) {
    const int b = blockIdx.x - P1B;   // 0 -> bq, 1 -> bk
    const int m = threadIdx.x;
    const float* bvec = (b == 0) ? bq : bk;
    const float alpha = (b == 0) ? QSCALE : 1.0f;
    float s = 0.0f;
    for (int j = 0; j < DD; ++j) s = fmaf(bvec[j], RF[m * DD + j], s);
    bcat[(b == 0 ? 0 : 256) + m] = s * alpha;
  } else {
    // edge count (degi pre-zeroed by hipMemsetAsync)
    int i = (blockIdx.x - P1B - 2) * 256 + threadIdx.x;
    if (i < EE) atomicAdd(&degi[ei[EE + i]], 1);
  }
}

// ---------------- MFMA GEMM v3: A-resident block, n-loop, full-rank swizzles ----------------
// 8 waves (quadrant q, k-half ks). A [64][256] staged once; per n-tile B [64][256]
// staged; slot swizzle = sl ^ (row&31) both sides (2 lanes/bank = free). 80 KB LDS,
// 2 blocks/CU. K fixed at 256.
// OMODE: 3 = qkv route (qb plain, kb 2-term sw, vbT^T ushort4);
//        6 = dual: blockIdx.y<128 -> xw (A@BT -> Cv bf16 N=256, NT);
//                  blockIdx.y>=128 -> fold (Cv2@Cv3 -> Cv4 Wcat routing, N=512, NT=4)
template<int OMODE, bool RELU>
__global__ __launch_bounds__(512, 2) void gemm_v3_kernel(
    const ushort* __restrict__ A, const ushort* __restrict__ BT,
    const float* __restrict__ bias, void* __restrict__ Cv,
    void* __restrict__ Cv2, void* __restrict__ Cv3, void* __restrict__ Cv4,
    int NT)
{
  __shared__ ushort As[16384];   // 32 KB
  __shared__ ushort Bs[16384];   // 32 KB
  __shared__ float  red[4096];   // 16 KB

  const int tid = threadIdx.x;
  const int c32 = tid & 31, hi = (tid >> 5) & 1;
  const int wv = tid >> 6;
  const int q = wv & 3, ks = wv >> 2;
  const int qm = (q >> 1) << 5, qn = (q & 1) << 5;

  const ushort* pA = A;
  const ushort* pBT = BT;
  int m0 = blockIdx.y * 64;
  int nt = NT;
  bool xw_path = true;
  if (OMODE == 6) {
    if (blockIdx.y >= 128) {
      xw_path = false;
      pA = (const ushort*)Cv2;              // RFb
      pBT = (const ushort*)Cv3;             // Wqkb
      m0 = (blockIdx.y - 128) * 64;
      nt = 4;                               // N=512, NS=2
    }
  }

  // stage A once (linear dest, source pre-swizzled: slot ^ (row&31))
#pragma unroll
  for (int i = 0; i < 4; ++i) {
    int c = tid + (i << 9);
    int row = c >> 5, psl = c & 31;
    int ssl = psl ^ (row & 31);
    async_copy16(&As[c << 3], &pA[(size_t)(m0 + row) * 256 + (ssl << 3)]);
  }

#define GSB(n0_) { \
    _Pragma("unroll") \
    for (int i = 0; i < 4; ++i) { \
      int c = tid + (i << 9); \
      int row = c >> 5, psl = c & 31; \
      int ssl = psl ^ (row & 31); \
      async_copy16(&Bs[c << 3], &pBT[(size_t)((n0_) + row) * 256 + (ssl << 3)]); \
    } }

  GSB((size_t)blockIdx.x * nt * 64)

  const int ra = qm + c32, rb = qn + c32;
  for (int j = 0; j < nt; ++j) {
    const int n0 = (blockIdx.x * nt + j) * 64;
    asm volatile("s_waitcnt vmcnt(0)" ::: "memory");
    __syncthreads();
    float16v acc = (float16v)(0.0f);
    __builtin_amdgcn_s_setprio(1);
#pragma unroll
    for (int kk = 0; kk < 8; ++kk) {
      const int sl = (((ks << 3) + kk) << 1) + hi;
      short8v af = *(const short8v*)&As[(ra << 8) + ((sl ^ c32) << 3)];
      short8v bf = *(const short8v*)&Bs[(rb << 8) + ((sl ^ c32) << 3)];
      acc = __builtin_amdgcn_mfma_f32_32x32x16_bf16(af, bf, acc, 0, 0, 0);
    }
    __builtin_amdgcn_s_setprio(0);
    __syncthreads();                       // all Bs reads done
    if (j + 1 < nt) GSB((size_t)(blockIdx.x * nt + j + 1) * 64)
    if (ks == 1) {
#pragma unroll
      for (int r = 0; r < 16; ++r) {
        const int crow = (r & 3) + ((r >> 2) << 3) + (hi << 2);
        red[(q << 10) + (crow << 5) + c32] = acc[r];
      }
    }
    __syncthreads();
    if (ks == 0) {
      const int col = n0 + qn + c32;
      const float bv = bias ? bias[col] : 0.0f;
      if (OMODE == 3 && col >= 512) {
        // vbT^T: ushort4 stores (4 consecutive m per group)
#pragma unroll
        for (int g = 0; g < 4; ++g) {
          float v0 = acc[g * 4 + 0] + red[(q << 10) + (((0) + (g << 3) + (hi << 2)) << 5) + c32] + bv;
          float v1 = acc[g * 4 + 1] + red[(q << 10) + (((1) + (g << 3) + (hi << 2)) << 5) + c32] + bv;
          float v2 = acc[g * 4 + 2] + red[(q << 10) + (((2) + (g << 3) + (hi << 2)) << 5) + c32] + bv;
          float v3 = acc[g * 4 + 3] + red[(q << 10) + (((3) + (g << 3) + (hi << 2)) << 5) + c32] + bv;
          ushort4 o; o.x = f2bf(v0); o.y = f2bf(v1); o.z = f2bf(v2); o.w = f2bf(v3);
          *(ushort4*)&((ushort*)Cv3)[(size_t)(col - 512) * NN + m0 + qm + (g << 3) + (hi << 2)] = o;
        }
      } else {
#pragma unroll
        for (int r = 0; r < 16; ++r) {
          const int crow = (r & 3) + ((r >> 2) << 3) + (hi << 2);
          const int m = m0 + qm + crow;
          float v = acc[r] + red[(q << 10) + (crow << 5) + c32] + bv;
          if (RELU) v = fmaxf(v, 0.0f);
          if (OMODE == 6) {
            if (xw_path) {
              ((ushort*)Cv)[(size_t)m * 256 + col] = f2bf(v);                     // xwb
            } else {
              ushort* W = (ushort*)Cv4;                                           // Wcat
              if (col < 256) W[(size_t)m * 256 + col] = f2bf(v);
              else W[(size_t)(256 + m) * 256 + (col - 256)] = f2bf(v);
            }
          } else {  // OMODE 3, col < 512
            if (col < 256) {
              ((ushort*)Cv)[(size_t)m * 256 + col] = f2bf(v);                       // qb plain
            } else {
              const int c2 = (col - 256) ^ ((m & 7) << 3) ^ (((m >> 3) & 3) << 6);  // kb 2-term swizzle
              ((ushort*)Cv2)[(size_t)m * 256 + c2] = f2bf(v);
            }
          }
        }
      }
    }
  }
#undef GSB
}

// ---------------- GCN gather + residual + LN1 (4 rows/block, wave per row, bf16 out only) ----------------
__global__ __launch_bounds__(256) void gcn_gather_ln_kernel(
    const ushort* __restrict__ xwb, const float* __restrict__ h,
    const float* __restrict__ dinv, const int* __restrict__ csr_off,
    const int* __restrict__ csr_src, const float* __restrict__ b_gcn,
    const float* __restrict__ g1, const float* __restrict__ be1,
    ushort* __restrict__ h1b)
{
  const int node = blockIdx.x * 4 + (threadIdx.x >> 6);
  const int t = threadIdx.x & 63;
  const int c4 = t << 2;
  const float di = dinv[node];
  const int e0 = csr_off[node], e1 = csr_off[node + 1];
  float acc[4] = {0.f, 0.f, 0.f, 0.f};
  for (int e = e0; e < e1; ++e) {
    int s = csr_src[e];
    float ds = dinv[s];
    ushort4 xv = *(const ushort4*)&xwb[(size_t)s * DD + c4];
    acc[0] = fmaf(b2f(xv.x), ds, acc[0]);
    acc[1] = fmaf(b2f(xv.y), ds, acc[1]);
    acc[2] = fmaf(b2f(xv.z), ds, acc[2]);
    acc[3] = fmaf(b2f(xv.w), ds, acc[3]);
  }
  ushort4 sv = *(const ushort4*)&xwb[(size_t)node * DD + c4];
  float4 hv = *(const float4*)&h[(size_t)node * DD + c4];
  float4 bg = *(const float4*)&b_gcn[c4];
  const float dii = di * di;
  float y[4];
  y[0] = fmaf(acc[0], di, b2f(sv.x) * dii) + bg.x + hv.x;
  y[1] = fmaf(acc[1], di, b2f(sv.y) * dii) + bg.y + hv.y;
  y[2] = fmaf(acc[2], di, b2f(sv.z) * dii) + bg.z + hv.z;
  y[3] = fmaf(acc[3], di, b2f(sv.w) * dii) + bg.w + hv.w;
  float s1 = (y[0] + y[1]) + (y[2] + y[3]);
  float s2 = (y[0]*y[0] + y[1]*y[1]) + (y[2]*y[2] + y[3]*y[3]);
#pragma unroll
  for (int m = 1; m <= 32; m <<= 1) { s1 += __shfl_xor(s1, m); s2 += __shfl_xor(s2, m); }
  float mu = s1 * (1.0f / 256.0f);
  float var = s2 * (1.0f / 256.0f) - mu * mu;
  float inv = rsqrtf(fmaxf(var, 0.0f) + 1e-5f);
  float4 g4 = *(const float4*)&g1[c4];
  float4 b4 = *(const float4*)&be1[c4];
  float v0 = (y[0] - mu) * inv * g4.x + b4.x;
  float v1 = (y[1] - mu) * inv * g4.y + b4.y;
  float v2 = (y[2] - mu) * inv * g4.z + b4.z;
  float v3 = (y[3] - mu) * inv * g4.w + b4.w;
  ushort4 ob; ob.x = f2bf(v0); ob.y = f2bf(v1); ob.z = f2bf(v2); ob.w = f2bf(v3);
  *(ushort4*)&h1b[(node << 8) + c4] = ob;
}

// ---------------- MFMA flash attention (round-9 exact: 0 conflicts, 81 us) ----------------
__global__ __launch_bounds__(256, 2) void flash_mfma_kernel(
    const ushort* __restrict__ qb, const ushort* __restrict__ kb,
    const ushort* __restrict__ vbT, ushort* __restrict__ opb,
    float* __restrict__ ml, int ksn, int kchunk)
{
  __shared__ ushort Kbuf[2][8192];   // [key 32][m 256], 2-term swizzled (from kb)
  __shared__ ushort Vbuf[2][8192];   // [d 256][key 32], slot ^ ((d>>3)&3)

  const int tid = threadIdx.x;
  const int l = tid & 63, wv = tid >> 6;
  const int c32 = l & 31, hi = l >> 5;
  const int qt = blockIdx.x / ksn, ks = blockIdx.x % ksn;
  const int q0 = qt * 128;
  const int kbase = ks * kchunk;

  const int vrow = tid >> 2;
  const ushort* kptr = kb + (size_t)(kbase + (tid >> 5)) * 256 + ((tid & 31) << 3);
  const ushort* vptr = vbT + (size_t)vrow * NN + kbase + (((tid & 3) ^ ((vrow >> 3) & 3)) << 3);

#define FSTAGE(b) { \
    _Pragma("unroll") \
    for (int c = 0; c < 4; ++c) { \
      async_copy16(&Kbuf[b][((c << 8) + tid) << 3], kptr + (size_t)c * (8 * 256)); \
      async_copy16(&Vbuf[b][((c << 8) + tid) << 3], vptr + (size_t)c * (64 * NN)); \
    } }

  FSTAGE(0)

  short8v qfr[16];
  {
    const ushort* qrow = qb + (size_t)(q0 + wv * 32 + c32) * 256 + (hi << 3);
#pragma unroll
    for (int kk = 0; kk < 16; ++kk)
      qfr[kk] = *(const short8v*)(qrow + (kk << 4));
  }

  float16v acc[8];
#pragma unroll
  for (int dt = 0; dt < 8; ++dt) acc[dt] = (float16v)(0.0f);
  float lsum = 0.f;

  const int ksw = ((c32 & 7) << 3) | (((c32 >> 3) & 3) << 6);
  const int vsw = (c32 >> 3) & 3;
  const int voff0 = (hi ^ vsw) << 3;
  const int voff1 = ((2 + hi) ^ vsw) << 3;

  const int nit = kchunk >> 5;
  for (int it = 0; it < nit; ++it) {
    asm volatile("s_waitcnt vmcnt(0)" ::: "memory");
    __syncthreads();
    if (it + 1 < nit) {
      kptr += 32 * 256;
      vptr += 32;
      FSTAGE((it + 1) & 1)
    }
    const ushort* Kp = Kbuf[it & 1];
    const ushort* Vp = Vbuf[it & 1];

    // ---- S[key][q] = K @ Q^T (32x32, k=256) ----
    float16v s = (float16v)(0.0f);
    __builtin_amdgcn_s_setprio(1);
#pragma unroll
    for (int kk = 0; kk < 16; ++kk) {
      short8v kf = *(const short8v*)&Kp[(c32 << 8) + (((kk << 4) + (hi << 3)) ^ ksw)];
      s = __builtin_amdgcn_mfma_f32_32x32x16_bf16(kf, qfr[kk], s, 0, 0, 0);
    }
    __builtin_amdgcn_s_setprio(0);

    // ---- p = exp2(s), deferred l, P->A-frag via cvt_pk + permlane32_swap ----
    float p[16];
#pragma unroll
    for (int r = 0; r < 16; ++r) p[r] = exp2f(s[r]);
    {
      float t0 = (p[0] + p[1]) + (p[2] + p[3]);
      float t1 = (p[4] + p[5]) + (p[6] + p[7]);
      float t2 = (p[8] + p[9]) + (p[10] + p[11]);
      float t3 = (p[12] + p[13]) + (p[14] + p[15]);
      lsum += (t0 + t1) + (t2 + t3);
    }
    unsigned u0, u1, u2, u3, u4, u5, u6, u7;
    asm("v_cvt_pk_bf16_f32 %0, %1, %2" : "=v"(u0) : "v"(p[0]),  "v"(p[1]));
    asm("v_cvt_pk_bf16_f32 %0, %1, %2" : "=v"(u1) : "v"(p[2]),  "v"(p[3]));
    asm("v_cvt_pk_bf16_f32 %0, %1, %2" : "=v"(u2) : "v"(p[4]),  "v"(p[5]));
    asm("v_cvt_pk_bf16_f32 %0, %1, %2" : "=v"(u3) : "v"(p[6]),  "v"(p[7]));
    asm("v_cvt_pk_bf16_f32 %0, %1, %2" : "=v"(u4) : "v"(p[8]),  "v"(p[9]));
    asm("v_cvt_pk_bf16_f32 %0, %1, %2" : "=v"(u5) : "v"(p[10]), "v"(p[11]));
    asm("v_cvt_pk_bf16_f32 %0, %1, %2" : "=v"(u6) : "v"(p[12]), "v"(p[13]));
    asm("v_cvt_pk_bf16_f32 %0, %1, %2" : "=v"(u7) : "v"(p[14]), "v"(p[15]));
    asm volatile("v_permlane32_swap_b32 %0, %1" : "+v"(u0), "+v"(u2));
    asm volatile("v_permlane32_swap_b32 %0, %1" : "+v"(u1), "+v"(u3));
    asm volatile("v_permlane32_swap_b32 %0, %1" : "+v"(u4), "+v"(u6));
    asm volatile("v_permlane32_swap_b32 %0, %1" : "+v"(u5), "+v"(u7));
    union { unsigned uu[4]; short8v v; } P0, P1;
    P0.uu[0] = u0; P0.uu[1] = u1; P0.uu[2] = u2; P0.uu[3] = u3;  // keys 0..15
    P1.uu[0] = u4; P1.uu[1] = u5; P1.uu[2] = u6; P1.uu[3] = u7;  // keys 16..31

    // ---- O[q][d] += P @ V (8 x 32x32x16, 2 k-halves) ----
    __builtin_amdgcn_s_setprio(1);
#pragma unroll
    for (int dt = 0; dt < 8; ++dt) {
      const int drow = (dt << 5) + c32;
      short8v vf0 = *(const short8v*)&Vp[(drow << 5) + voff0];
      short8v vf1 = *(const short8v*)&Vp[(drow << 5) + voff1];
      acc[dt] = __builtin_amdgcn_mfma_f32_32x32x16_bf16(P0.v, vf0, acc[dt], 0, 0, 0);
      acc[dt] = __builtin_amdgcn_mfma_f32_32x32x16_bf16(P1.v, vf1, acc[dt], 0, 0, 0);
    }
    __builtin_amdgcn_s_setprio(0);
  }
#undef FSTAGE

  float lt = lsum + __shfl_xor(lsum, 32);
  if (hi == 0) ml[(size_t)ks * NN + q0 + wv * 32 + c32] = lt;
  ushort* op = opb + (size_t)ks * (NN * DD);
#pragma unroll
  for (int dt = 0; dt < 8; ++dt)
#pragma unroll
    for (int r = 0; r < 16; ++r) {
      const int qrow = q0 + wv * 32 + (r & 3) + ((r >> 2) << 3) + (hi << 2);
      op[(size_t)qrow * DD + (dt << 5) + c32] = f2bf(acc[dt][r]);
    }
}

// ---------------- FUSED epilogue: merge + Wo-proj + LN2 + FFN1(relu) + FFN2 + LN3 ----------------
__global__ __launch_bounds__(512, 4) void epilogue_kernel(
    const ushort* __restrict__ opb, const float* __restrict__ ml,
    const ushort* __restrict__ h1b,
    const ushort* __restrict__ WoT, const float* __restrict__ bo,
    const float* __restrict__ g2, const float* __restrict__ be2,
    const ushort* __restrict__ W1T, const float* __restrict__ b1,
    const ushort* __restrict__ W2T, const float* __restrict__ b2,
    const float* __restrict__ g3, const float* __restrict__ be3,
    float* __restrict__ out, int ksn)
{
  __shared__ float  yL[32 * 256];    // 32 KB: y, then h2 (f32) after LN2
  __shared__ ushort h2bL[32 * 256];  // 16 KB swizzled
  __shared__ ushort tL[32 * 512];    // 32 KB swizzled; hgL aliases first 16 KB; y2L f32 later

  ushort* hgL = tL;                  // [32][256] bf16, slot-swizzled

  const int tid = threadIdx.x;
  const int c32 = tid & 31, hi = (tid >> 5) & 1;
  const int wv = tid >> 6;           // 0..7
  const int lane = tid & 63;
  const int m0 = blockIdx.x * 32;
  const int n0 = wv << 5;            // 32-col group for S1/S5
  const int col = n0 + c32;

  // ---- S0: merge partials -> hgL (bf16, swizzled) ----
  {
    const int row = tid >> 4;               // 0..31
    const int cseg = (tid & 15) << 4;       // 16 cols
    const int growp = m0 + row;
    float L = 0.f;
    for (int i = 0; i < ksn; ++i) L += ml[(size_t)i * NN + growp];
    const float invl = 1.0f / L;
    float num[16];
#pragma unroll
    for (int j = 0; j < 16; ++j) num[j] = 0.f;
    for (int i = 0; i < ksn; ++i) {
      const ushort* src = opb + (size_t)i * ((size_t)NN * DD) + (size_t)growp * DD + cseg;
      short8v v0 = *(const short8v*)src;
      short8v v1 = *(const short8v*)(src + 8);
#pragma unroll
      for (int j = 0; j < 8; ++j) {
        num[j]     += b2f((ushort)v0[j]);
        num[8 + j] += b2f((ushort)v1[j]);
      }
    }
    const int swz = (row & 7) ^ (((row >> 3) & 3) << 3);
    const int sl0 = (cseg >> 3);
    union { ushort us[8]; short8v v; } o0, o1;
#pragma unroll
    for (int j = 0; j < 8; ++j) {
      o0.us[j] = f2bf(num[j] * invl);
      o1.us[j] = f2bf(num[8 + j] * invl);
    }
    *(short8v*)&hgL[(row << 8) + ((sl0 ^ swz) << 3)] = o0.v;
    *(short8v*)&hgL[(row << 8) + (((sl0 + 1) ^ swz) << 3)] = o1.v;
  }
  __syncthreads();

  // ---- S1: Wo GEMM C[32][256] (A from hgL) ----
  float16v acc = (float16v)(0.0f);
  {
    const int aswz = (c32 & 7) ^ (((c32 >> 3) & 3) << 3);
#pragma unroll
    for (int k0 = 0; k0 < 256; k0 += 16) {
      const int sA = (k0 >> 3) + hi;
      short8v af = *(const short8v*)&hgL[(c32 << 8) + ((sA ^ aswz) << 3)];
      short8v bf = *(const short8v*)&WoT[(size_t)col * 256 + k0 + (hi << 3)];
      acc = __builtin_amdgcn_mfma_f32_32x32x16_bf16(af, bf, acc, 0, 0, 0);
    }
  }
  // ---- S2: y = C + bo + h1 (bf16) -> yL ----
  {
    const float bov = bo[col];
#pragma unroll
    for (int r = 0; r < 16; ++r) {
      const int row = (r & 3) + ((r >> 2) << 3) + (hi << 2);
      yL[(row << 8) + col] = acc[r] + bov + b2f(h1b[(size_t)(m0 + row) * 256 + col]);
    }
  }
  __syncthreads();
  // ---- S3: LN2 ----
#pragma unroll
  for (int rr = 0; rr < 4; ++rr) {
    const int row = (wv << 2) + rr;
    const int c4 = lane << 2;
    float4 v = *(const float4*)&yL[(row << 8) + c4];
    float s1 = (v.x + v.y) + (v.z + v.w);
    float s2 = (v.x * v.x + v.y * v.y) + (v.z * v.z + v.w * v.w);
#pragma unroll
    for (int m = 1; m <= 32; m <<= 1) { s1 += __shfl_xor(s1, m); s2 += __shfl_xor(s2, m); }
    float mu = s1 * (1.0f / 256.0f);
    float var = s2 * (1.0f / 256.0f) - mu * mu;
    float inv = rsqrtf(fmaxf(var, 0.0f) + 1e-5f);
    float4 g4 = *(const float4*)&g2[c4];
    float4 b4 = *(const float4*)&be2[c4];
    float o0 = (v.x - mu) * inv * g4.x + b4.x;
    float o1 = (v.y - mu) * inv * g4.y + b4.y;
    float o2 = (v.z - mu) * inv * g4.z + b4.z;
    float o3 = (v.w - mu) * inv * g4.w + b4.w;
    *(float4*)&yL[(row << 8) + c4] = make_float4(o0, o1, o2, o3);
    const int psl = (c4 >> 3) ^ (row & 7);
    ushort4 ob; ob.x = f2bf(o0); ob.y = f2bf(o1); ob.z = f2bf(o2); ob.w = f2bf(o3);
    *(ushort4*)&h2bL[(row << 8) + (psl << 3) + (c4 & 7)] = ob;
  }
  __syncthreads();
  // ---- S4: FFN1 (relu) ----
  {
    float16v a1[2] = {(float16v)(0.0f), (float16v)(0.0f)};
    const int f0 = wv << 6;
#pragma unroll
    for (int k0 = 0; k0 < 256; k0 += 16) {
      const int s = (k0 >> 3) + hi;
      short8v af = *(const short8v*)&h2bL[(c32 << 8) + ((s ^ (c32 & 7)) << 3)];
#pragma unroll
      for (int nt = 0; nt < 2; ++nt) {
        short8v bf = *(const short8v*)&W1T[(size_t)(f0 + (nt << 5) + c32) * 256 + k0 + (hi << 3)];
        a1[nt] = __builtin_amdgcn_mfma_f32_32x32x16_bf16(af, bf, a1[nt], 0, 0, 0);
      }
    }
#pragma unroll
    for (int nt = 0; nt < 2; ++nt) {
      const int col1 = f0 + (nt << 5) + c32;
      const float b1v = b1[col1];
#pragma unroll
      for (int r = 0; r < 16; ++r) {
        const int row = (r & 3) + ((r >> 2) << 3) + (hi << 2);
        float v = fmaxf(a1[nt][r] + b1v, 0.0f);
        const int psl = (col1 >> 3) ^ (row & 7);
        tL[(row << 9) + (psl << 3) + (col1 & 7)] = f2bf(v);
      }
    }
  }
  __syncthreads();
  // ---- S5: FFN2 (+ h2 residual) ----
  float16v a2 = (float16v)(0.0f);
#pragma unroll
  for (int k0 = 0; k0 < 512; k0 += 16) {
    const int s = (k0 >> 3) + hi;
    short8v af = *(const short8v*)&tL[(c32 << 9) + ((s ^ (c32 & 7)) << 3)];
    short8v bf = *(const short8v*)&W2T[(size_t)col * 512 + k0 + (hi << 3)];
    a2 = __builtin_amdgcn_mfma_f32_32x32x16_bf16(af, bf, a2, 0, 0, 0);
  }
  {
    const float b2v = b2[col];
#pragma unroll
    for (int r = 0; r < 16; ++r) {
      const int row = (r & 3) + ((r >> 2) << 3) + (hi << 2);
      a2[r] += b2v + yL[(row << 8) + col];   // + h2 residual
    }
  }
  __syncthreads();                            // all tL reads complete
  {
    float* y2L = (float*)tL;
#pragma unroll
    for (int r = 0; r < 16; ++r) {
      const int row = (r & 3) + ((r >> 2) << 3) + (hi << 2);
      y2L[(row << 8) + col] = a2[r];
    }
  }
  __syncthreads();
  // ---- S6: LN3 -> out ----
  {
    const float* y2L = (const float*)tL;
#pragma unroll
    for (int rr = 0; rr < 4; ++rr) {
      const int row = (wv << 2) + rr;
      const int c4 = lane << 2;
      float4 v = *(const float4*)&y2L[(row << 8) + c4];
      float s1 = (v.x + v.y) + (v.z + v.w);
      float s2 = (v.x * v.x + v.y * v.y) + (v.z * v.z + v.w * v.w);
#pragma unroll
      for (int m = 1; m <= 32; m <<= 1) { s1 += __shfl_xor(s1, m); s2 += __shfl_xor(s2, m); }
      float mu = s1 * (1.0f / 256.0f);
      float var = s2 * (1.0f / 256.0f) - mu * mu;
      float inv = rsqrtf(fmaxf(var, 0.0f) + 1e-5f);
      float4 g4 = *(const float4*)&g3[c4];
      float4 b4 = *(const float4*)&be3[c4];
      float4 o;
      o.x = (v.x - mu) * inv * g4.x + b4.x;
      o.y = (v.y - mu) * inv * g4.y + b4.y;
      o.z = (v.z - mu) * inv * g4.z + b4.z;
      o.w = (v.w - mu) * inv * g4.w + b4.w;
      *(float4*)&out[(size_t)(m0 + row) * 256 + c4] = o;
    }
  }
}

extern "C" void kernel_launch(void* const* d_in, const int* in_sizes, int n_in,
                              void* d_out, int out_size, void* d_ws, size_t ws_size,
                              hipStream_t stream) {
  (void)in_sizes; (void)n_in; (void)out_size;
  const float* h     = (const float*)d_in[0];
  const int*   ei    = (const int*)  d_in[1];
  const float* W_gcn = (const float*)d_in[2];
  const float* b_gcn = (const float*)d_in[3];
  const float* Wq    = (const float*)d_in[4];
  const float* bq    = (const float*)d_in[5];
  const float* Wk    = (const float*)d_in[6];
  const float* bk    = (const float*)d_in[7];
  const float* Wv    = (const float*)d_in[8];
  const float* bv    = (const float*)d_in[9];
  const float* Wo    = (const float*)d_in[10];
  const float* bo    = (const float*)d_in[11];
  const float* RF    = (const float*)d_in[12];
  const float* g1    = (const float*)d_in[13];
  const float* be1   = (const float*)d_in[14];
  const float* g2    = (const float*)d_in[15];
  const float* be2   = (const float*)d_in[16];
  const float* g3    = (const float*)d_in[17];
  const float* be3   = (const float*)d_in[18];
  const float* W1    = (const float*)d_in[19];
  const float* b1    = (const float*)d_in[20];
  const float* W2    = (const float*)d_in[21];
  const float* b2    = (const float*)d_in[22];
  float* out = (float*)d_out;

  const size_t M2 = (size_t)NN * DD;
  const int ksn = (ws_size >= (size_t)64 * 1024 * 1024) ? 8 : 4;
  const int kchunk = NN / ksn;

  char* base = (char*)d_ws;
  ushort* hbX  = (ushort*)base; base += M2 * 2;
  ushort* h1bX = (ushort*)base; base += M2 * 2;
  ushort* qb   = (ushort*)base; base += M2 * 2;
  ushort* kb   = (ushort*)base; base += M2 * 2;
  ushort* vbT  = (ushort*)base; base += M2 * 2;
  ushort* opb  = (ushort*)base;
  float*  R    = (float*)opb;   base += (size_t)ksn * M2 * 2;
  float*  mlf  = (float*)base;  base += (size_t)8 * NN * 4;
  ushort* WgcnT = (ushort*)base; base += DD * DD * 2;
  ushort* Wcat  = (ushort*)base; base += (size_t)768 * DD * 2;
  ushort* WoT   = (ushort*)base; base += DD * DD * 2;
  ushort* W1T   = (ushort*)base; base += FF * DD * 2;
  ushort* W2T   = (ushort*)base; base += DD * FF * 2;
  ushort* RFb   = (ushort*)base; base += DD * DD * 2;
  ushort* Wqkb  = (ushort*)base; base += (size_t)2 * DD * DD * 2;
  float*  bcat  = (float*)base;  base += 768 * 4;
  float*  dinv  = (float*)base;  base += NN * 4;
  int* degi    = (int*)base; base += NN * 4;
  int* cursor  = (int*)base; base += NN * 4;
  int* csr_off = (int*)base; base += (NN + 4) * 4;
  int* csr_src = (int*)base; base += EE * 4;

  // aliases
  ushort* xwb = (ushort*)R;        // bf16 xw, pre-flash (R region is opb during flash)

  // zero degi + cursor (contiguous)
  hipMemsetAsync(degi, 0, (size_t)2 * NN * sizeof(int), stream);

  // fused precompute (+ bias folds + edge count)
  prep_kernel<<<P1B + 2 + 1024, 256, 0, stream>>>(
      h, W_gcn, Wv, Wo, W1, W2, bv, Wq, Wk, bq, bk, RF, ei,
      hbX, WgcnT, Wcat, WoT, W1T, W2T, RFb, Wqkb, bcat, degi);

  // dual GEMM: xw = hb @ WgcnT (NT=2)  AND  Wcat[q|k] = RFb @ Wqkb (NT=4)
  gemm_v3_kernel<6, false><<<dim3(2, 132), 512, 0, stream>>>(
      hbX, WgcnT, nullptr, xwb, RFb, Wqkb, Wcat, 2);

  // CSR
  scan_kernel<<<1, 1024, 0, stream>>>(degi, csr_off, dinv);
  fill_kernel<<<EE / 256, 256, 0, stream>>>(ei, csr_off, cursor, csr_src);

  // local GCN + LN1 (bf16 out)
  gcn_gather_ln_kernel<<<NN / 4, 256, 0, stream>>>(xwb, h, dinv, csr_off, csr_src, b_gcn, g1, be1, h1bX);
  // fused q/k/v projections (A-resident GEMM, routed epilogue)
  gemm_v3_kernel<3, false><<<dim3(4, 128), 512, 0, stream>>>(
      h1bX, Wcat, bcat, qb, kb, vbT, nullptr, 3);
  // attention (128 q-rows/block, 2 blocks/CU)
  flash_mfma_kernel<<<(NN / 128) * ksn, 256, 0, stream>>>(qb, kb, vbT, opb, mlf, ksn, kchunk);
  // fused merge + Wo + LN2 + FFN + LN3 -> out
  epilogue_kernel<<<NN / 32, 512, 0, stream>>>(
      opb, mlf, h1bX, WoT, bo, g2, be2, W1T, b1, W2T, b2, g3, be3, out, ksn);
}

// Round 15
// 203.095 us; speedup vs baseline: 1.0565x; 1.0565x over previous
//
#include <hip/hip_runtime.h>
#include <hip/hip_bf16.h>

#define NN 8192
#define EE 262144
#define DD 256
#define FF 512
#define MM 256

typedef __attribute__((ext_vector_type(8))) short short8v;
typedef __attribute__((ext_vector_type(16))) float float16v;

__device__ __forceinline__ ushort f2bf(float x) {
  union { float f; unsigned u; } c; c.f = x;
  unsigned r = (c.u + 0x7FFF + ((c.u >> 16) & 1)) >> 16;
  return (ushort)r;
}
__device__ __forceinline__ float b2f(ushort u) {
  union { unsigned u; float f; } c; c.u = ((unsigned)u) << 16;
  return c.f;
}
__device__ __forceinline__ void async_copy16(void* lds, const void* g) {
  __builtin_amdgcn_global_load_lds(
      (const __attribute__((address_space(1))) void*)g,
      (__attribute__((address_space(3))) void*)lds, 16, 0, 0);
}

// ---------------- CSR scan / fill ----------------
__global__ __launch_bounds__(1024) void scan_kernel(const int* __restrict__ degi,
                                                    int* __restrict__ csr_off,
                                                    float* __restrict__ dinv) {
  __shared__ int part[1024];
  int tid = threadIdx.x;
  int base = tid * 8;
  int loc[8], dv[8]; int s = 0;
#pragma unroll
  for (int i = 0; i < 8; ++i) { int d = degi[base + i]; dv[i] = d; loc[i] = s; s += d; }
  part[tid] = s;
  __syncthreads();
  for (int off = 1; off < 1024; off <<= 1) {
    int v = (tid >= off) ? part[tid - off] : 0;
    __syncthreads();
    part[tid] += v;
    __syncthreads();
  }
  int pre = (tid == 0) ? 0 : part[tid - 1];
#pragma unroll
  for (int i = 0; i < 8; ++i) {
    csr_off[base + i] = pre + loc[i];
    dinv[base + i] = rsqrtf((float)(dv[i] + 1));  // +1 self loop
  }
  if (tid == 1023) csr_off[NN] = part[1023];
}

__global__ void fill_kernel(const int* __restrict__ ei, const int* __restrict__ csr_off,
                            int* __restrict__ cursor, int* __restrict__ csr_src) {
  int i = blockIdx.x * blockDim.x + threadIdx.x;
  if (i < EE) {
    int d = ei[EE + i];
    int pos = csr_off[d] + atomicAdd(&cursor[d], 1);
    csr_src[pos] = ei[i];
  }
}

// ---------------- fused precompute: converts + bias folds + edge COUNT ----------------
#define QSCALE 0.090168441f   // log2(e) / 16
#define P1B 10753             // ceil(2752768 / 256)
__global__ __launch_bounds__(256) void prep_kernel(
    const float* __restrict__ h, const float* __restrict__ W_gcn,
    const float* __restrict__ Wv, const float* __restrict__ Wo,
    const float* __restrict__ W1, const float* __restrict__ W2,
    const float* __restrict__ bv,
    const float* __restrict__ Wq, const float* __restrict__ Wk,
    const float* __restrict__ bq, const float* __restrict__ bk,
    const float* __restrict__ RF, const int* __restrict__ ei,
    ushort* __restrict__ hb, ushort* __restrict__ WgcnT, ushort* __restrict__ Wcat,
    ushort* __restrict__ WoT, ushort* __restrict__ W1T, ushort* __restrict__ W2T,
    ushort* __restrict__ RFb, ushort* __restrict__ Wqkb,
    float* __restrict__ bcat, int* __restrict__ degi)
{
  if (blockIdx.x < P1B) {
    int i = blockIdx.x * 256 + threadIdx.x;
    const int R0 = NN * DD;
    const int R1 = R0 + DD * DD;
    const int R2 = R1 + DD * DD;
    const int R3 = R2 + DD * DD;
    const int R4 = R3 + DD * FF;
    const int R5 = R4 + FF * DD;
    const int R6 = R5 + DD;
    const int R7 = R6 + DD * DD;
    const int R8 = R7 + DD * DD;
    const int R9 = R8 + DD * DD;
    if (i < R0) {
      hb[i] = f2bf(h[i]);
    } else if (i < R1) {
      int j = i - R0; int n = j >> 8, k = j & 255;
      WgcnT[(n << 8) | k] = f2bf(W_gcn[k * DD + n]);
    } else if (i < R2) {
      int j = i - R1; int n = j >> 8, k = j & 255;
      Wcat[((512 + n) << 8) | k] = f2bf(Wv[k * DD + n]);
    } else if (i < R3) {
      int j = i - R2; int n = j >> 8, k = j & 255;
      WoT[(n << 8) | k] = f2bf(Wo[k * DD + n]);
    } else if (i < R4) {
      int j = i - R3; int n = j >> 8, k = j & 255;
      W1T[(n << 8) | k] = f2bf(W1[k * FF + n]);
    } else if (i < R5) {
      int j = i - R4; int n = j >> 9, k = j & 511;
      W2T[n * FF + k] = f2bf(W2[k * DD + n]);
    } else if (i < R6) {
      bcat[512 + (i - R5)] = bv[i - R5];
    } else if (i < R7) {
      int j = i - R6;
      RFb[j] = f2bf(RF[j]);                       // RF [m][t] plain
    } else if (i < R8) {
      int j = i - R7;
      Wqkb[j] = f2bf(Wq[j] * QSCALE);             // rows 0-255: Wq [d][t] scaled
    } else if (i < R9) {
      int j = i - R8;
      Wqkb[DD * DD + j] = f2bf(Wk[j]);            // rows 256-511: Wk [d][t]
    }
  } else if (blockIdx.x < P1B + 2) {
    const int b = blockIdx.x - P1B;   // 0 -> bq, 1 -> bk
    const int m = threadIdx.x;
    const float* bvec = (b == 0) ? bq : bk;
    const float alpha = (b == 0) ? QSCALE : 1.0f;
    float s = 0.0f;
    for (int j = 0; j < DD; ++j) s = fmaf(bvec[j], RF[m * DD + j], s);
    bcat[(b == 0 ? 0 : 256) + m] = s * alpha;
  } else {
    // edge count (degi pre-zeroed by hipMemsetAsync)
    int i = (blockIdx.x - P1B - 2) * 256 + threadIdx.x;
    if (i < EE) atomicAdd(&degi[ei[EE + i]], 1);
  }
}

// ---------------- MFMA GEMM v2: 8 waves, 64x64 tile, in-block K-split, 32x32x16 ----------------
// OMODE: 3 = qkv route (qb plain, kb 2-term sw, vbT^T ushort4); 4 = bf16 plain;
//        6 = dual: blockIdx.y<128 -> xw (A@BT -> Cv bf16, N=256);
//                  blockIdx.y>=128 -> fold (Cv2@Cv3 -> Cv4 Wcat routing, N=512)
template<int OMODE, bool RELU>
__global__ __launch_bounds__(512) void gemm_bf16_kernel(
    const ushort* __restrict__ A, const ushort* __restrict__ BT,
    const float* __restrict__ bias, void* __restrict__ Cv,
    void* __restrict__ Cv2, void* __restrict__ Cv3, void* __restrict__ Cv4,
    int M, int N, int K)
{
  __shared__ ushort As[2][4096];
  __shared__ ushort Bs[2][4096];
  const int tid = threadIdx.x;
  const int c32 = tid & 31, hi = (tid >> 5) & 1;
  const int wv = tid >> 6;
  const int q = wv & 3, ks = wv >> 2;
  const int qm = (q >> 1) << 5, qn = (q & 1) << 5;

  const ushort* pA = A;
  const ushort* pBT = BT;
  int m0 = blockIdx.y * 64;
  const int n0 = blockIdx.x * 64;
  bool xw_path = true;
  if (OMODE == 6) {
    if (blockIdx.y < 128) {
      if (blockIdx.x >= 4) return;          // xw N=256
    } else {
      xw_path = false;
      pA = (const ushort*)Cv2;              // RFb
      pBT = (const ushort*)Cv3;             // Wqkb
      m0 = (blockIdx.y - 128) * 64;
    }
  }

  const int sr = tid >> 3, spsl = tid & 7;
  const int ssl = spsl ^ ((sr >> 2) & 7);
  const ushort* Asrc = pA + (size_t)(m0 + sr) * K + (ssl << 3);
  const ushort* Bsrc = pBT + (size_t)(n0 + sr) * K + (ssl << 3);

  const int ra = qm + c32, rb = qn + c32;
  const int ga = (ra >> 2) & 7, gb = (rb >> 2) & 7;

  float16v acc = (float16v)(0.0f);

#define GS(b, k0) { \
    async_copy16(&As[b][tid << 3], Asrc + (k0)); \
    async_copy16(&Bs[b][tid << 3], Bsrc + (k0)); }

  GS(0, 0)
  const int nk = K >> 6;
  for (int kt = 0; kt < nk; ++kt) {
    asm volatile("s_waitcnt vmcnt(0)" ::: "memory");
    __syncthreads();
    if (kt + 1 < nk) GS((kt + 1) & 1, (kt + 1) << 6)
    const ushort* as_ = As[kt & 1];
    const ushort* bs_ = Bs[kt & 1];
    __builtin_amdgcn_s_setprio(1);
#pragma unroll
    for (int k2 = 0; k2 < 2; ++k2) {
      const int k16 = (ks << 1) + k2;
      const int sl = (k16 << 1) + hi;
      short8v af = *(const short8v*)&as_[(ra << 6) + ((sl ^ ga) << 3)];
      short8v bf = *(const short8v*)&bs_[(rb << 6) + ((sl ^ gb) << 3)];
      acc = __builtin_amdgcn_mfma_f32_32x32x16_bf16(af, bf, acc, 0, 0, 0);
    }
    __builtin_amdgcn_s_setprio(0);
  }
#undef GS

  __syncthreads();
  float* red = (float*)&As[0][0];
  if (ks == 1) {
#pragma unroll
    for (int r = 0; r < 16; ++r) {
      const int crow = (r & 3) + ((r >> 2) << 3) + (hi << 2);
      red[(q << 10) + (crow << 5) + c32] = acc[r];
    }
  }
  __syncthreads();
  if (ks == 0) {
    const int col = n0 + qn + c32;
    const float bv = bias ? bias[col] : 0.0f;
    if (OMODE == 3 && col >= 512) {
      // vbT^T: ushort4 stores (4 consecutive m per group)
#pragma unroll
      for (int g = 0; g < 4; ++g) {
        float v0 = acc[g * 4 + 0] + red[(q << 10) + (((0) + (g << 3) + (hi << 2)) << 5) + c32] + bv;
        float v1 = acc[g * 4 + 1] + red[(q << 10) + (((1) + (g << 3) + (hi << 2)) << 5) + c32] + bv;
        float v2 = acc[g * 4 + 2] + red[(q << 10) + (((2) + (g << 3) + (hi << 2)) << 5) + c32] + bv;
        float v3 = acc[g * 4 + 3] + red[(q << 10) + (((3) + (g << 3) + (hi << 2)) << 5) + c32] + bv;
        ushort4 o; o.x = f2bf(v0); o.y = f2bf(v1); o.z = f2bf(v2); o.w = f2bf(v3);
        *(ushort4*)&((ushort*)Cv3)[(size_t)(col - 512) * NN + m0 + qm + (g << 3) + (hi << 2)] = o;
      }
    } else {
#pragma unroll
      for (int r = 0; r < 16; ++r) {
        const int crow = (r & 3) + ((r >> 2) << 3) + (hi << 2);
        const int m = m0 + qm + crow;
        float v = acc[r] + red[(q << 10) + (crow << 5) + c32] + bv;
        if (RELU) v = fmaxf(v, 0.0f);
        if (OMODE == 4) {
          ((ushort*)Cv)[(size_t)m * N + col] = f2bf(v);
        } else if (OMODE == 6) {
          if (xw_path) {
            ((ushort*)Cv)[(size_t)m * 256 + col] = f2bf(v);                     // xwb
          } else {
            ushort* W = (ushort*)Cv4;                                           // Wcat
            if (col < 256) W[(size_t)m * 256 + col] = f2bf(v);
            else W[(size_t)(256 + m) * 256 + (col - 256)] = f2bf(v);
          }
        } else {  // OMODE 3, col < 512
          if (col < 256) {
            ((ushort*)Cv)[(size_t)m * 256 + col] = f2bf(v);                       // qb plain
          } else {
            const int c2 = (col - 256) ^ ((m & 7) << 3) ^ (((m >> 3) & 3) << 6);  // kb 2-term swizzle
            ((ushort*)Cv2)[(size_t)m * 256 + c2] = f2bf(v);
          }
        }
      }
    }
  }
}

// ---------------- GCN gather + residual + LN1 (4 rows/block; 4-deep pipelined edge loop) ----------------
__global__ __launch_bounds__(256) void gcn_gather_ln_kernel(
    const ushort* __restrict__ xwb, const float* __restrict__ h,
    const float* __restrict__ dinv, const int* __restrict__ csr_off,
    const int* __restrict__ csr_src, const float* __restrict__ b_gcn,
    const float* __restrict__ g1, const float* __restrict__ be1,
    ushort* __restrict__ h1b)
{
  const int node = blockIdx.x * 4 + (threadIdx.x >> 6);
  const int t = threadIdx.x & 63;
  const int c4 = t << 2;
  const float di = dinv[node];
  const int e0 = csr_off[node], e1 = csr_off[node + 1];
  float acc[4] = {0.f, 0.f, 0.f, 0.f};
  int e = e0;
  // 4-deep pipelined main loop: 4 independent idx loads, then 8 independent data loads
  for (; e + 4 <= e1; e += 4) {
    int s0 = csr_src[e + 0];
    int s1 = csr_src[e + 1];
    int s2 = csr_src[e + 2];
    int s3 = csr_src[e + 3];
    float dA = dinv[s0], dB = dinv[s1], dC = dinv[s2], dE = dinv[s3];
    ushort4 x0 = *(const ushort4*)&xwb[(size_t)s0 * DD + c4];
    ushort4 x1 = *(const ushort4*)&xwb[(size_t)s1 * DD + c4];
    ushort4 x2 = *(const ushort4*)&xwb[(size_t)s2 * DD + c4];
    ushort4 x3 = *(const ushort4*)&xwb[(size_t)s3 * DD + c4];
    acc[0] = fmaf(b2f(x0.x), dA, acc[0]);
    acc[1] = fmaf(b2f(x0.y), dA, acc[1]);
    acc[2] = fmaf(b2f(x0.z), dA, acc[2]);
    acc[3] = fmaf(b2f(x0.w), dA, acc[3]);
    acc[0] = fmaf(b2f(x1.x), dB, acc[0]);
    acc[1] = fmaf(b2f(x1.y), dB, acc[1]);
    acc[2] = fmaf(b2f(x1.z), dB, acc[2]);
    acc[3] = fmaf(b2f(x1.w), dB, acc[3]);
    acc[0] = fmaf(b2f(x2.x), dC, acc[0]);
    acc[1] = fmaf(b2f(x2.y), dC, acc[1]);
    acc[2] = fmaf(b2f(x2.z), dC, acc[2]);
    acc[3] = fmaf(b2f(x2.w), dC, acc[3]);
    acc[0] = fmaf(b2f(x3.x), dE, acc[0]);
    acc[1] = fmaf(b2f(x3.y), dE, acc[1]);
    acc[2] = fmaf(b2f(x3.z), dE, acc[2]);
    acc[3] = fmaf(b2f(x3.w), dE, acc[3]);
  }
  for (; e < e1; ++e) {
    int s = csr_src[e];
    float ds = dinv[s];
    ushort4 xv = *(const ushort4*)&xwb[(size_t)s * DD + c4];
    acc[0] = fmaf(b2f(xv.x), ds, acc[0]);
    acc[1] = fmaf(b2f(xv.y), ds, acc[1]);
    acc[2] = fmaf(b2f(xv.z), ds, acc[2]);
    acc[3] = fmaf(b2f(xv.w), ds, acc[3]);
  }
  ushort4 sv = *(const ushort4*)&xwb[(size_t)node * DD + c4];
  float4 hv = *(const float4*)&h[(size_t)node * DD + c4];
  float4 bg = *(const float4*)&b_gcn[c4];
  const float dii = di * di;
  float y[4];
  y[0] = fmaf(acc[0], di, b2f(sv.x) * dii) + bg.x + hv.x;
  y[1] = fmaf(acc[1], di, b2f(sv.y) * dii) + bg.y + hv.y;
  y[2] = fmaf(acc[2], di, b2f(sv.z) * dii) + bg.z + hv.z;
  y[3] = fmaf(acc[3], di, b2f(sv.w) * dii) + bg.w + hv.w;
  float s1 = (y[0] + y[1]) + (y[2] + y[3]);
  float s2 = (y[0]*y[0] + y[1]*y[1]) + (y[2]*y[2] + y[3]*y[3]);
#pragma unroll
  for (int m = 1; m <= 32; m <<= 1) { s1 += __shfl_xor(s1, m); s2 += __shfl_xor(s2, m); }
  float mu = s1 * (1.0f / 256.0f);
  float var = s2 * (1.0f / 256.0f) - mu * mu;
  float inv = rsqrtf(fmaxf(var, 0.0f) + 1e-5f);
  float4 g4 = *(const float4*)&g1[c4];
  float4 b4 = *(const float4*)&be1[c4];
  float v0 = (y[0] - mu) * inv * g4.x + b4.x;
  float v1 = (y[1] - mu) * inv * g4.y + b4.y;
  float v2 = (y[2] - mu) * inv * g4.z + b4.z;
  float v3 = (y[3] - mu) * inv * g4.w + b4.w;
  ushort4 ob; ob.x = f2bf(v0); ob.y = f2bf(v1); ob.z = f2bf(v2); ob.w = f2bf(v3);
  *(ushort4*)&h1b[(node << 8) + c4] = ob;
}

// ---------------- MFMA flash attention (round-9 exact: 0 conflicts, 81 us) ----------------
__global__ __launch_bounds__(256, 2) void flash_mfma_kernel(
    const ushort* __restrict__ qb, const ushort* __restrict__ kb,
    const ushort* __restrict__ vbT, ushort* __restrict__ opb,
    float* __restrict__ ml, int ksn, int kchunk)
{
  __shared__ ushort Kbuf[2][8192];   // [key 32][m 256], 2-term swizzled (from kb)
  __shared__ ushort Vbuf[2][8192];   // [d 256][key 32], slot ^ ((d>>3)&3)

  const int tid = threadIdx.x;
  const int l = tid & 63, wv = tid >> 6;
  const int c32 = l & 31, hi = l >> 5;
  const int qt = blockIdx.x / ksn, ks = blockIdx.x % ksn;
  const int q0 = qt * 128;
  const int kbase = ks * kchunk;

  const int vrow = tid >> 2;
  const ushort* kptr = kb + (size_t)(kbase + (tid >> 5)) * 256 + ((tid & 31) << 3);
  const ushort* vptr = vbT + (size_t)vrow * NN + kbase + (((tid & 3) ^ ((vrow >> 3) & 3)) << 3);

#define FSTAGE(b) { \
    _Pragma("unroll") \
    for (int c = 0; c < 4; ++c) { \
      async_copy16(&Kbuf[b][((c << 8) + tid) << 3], kptr + (size_t)c * (8 * 256)); \
      async_copy16(&Vbuf[b][((c << 8) + tid) << 3], vptr + (size_t)c * (64 * NN)); \
    } }

  FSTAGE(0)

  short8v qfr[16];
  {
    const ushort* qrow = qb + (size_t)(q0 + wv * 32 + c32) * 256 + (hi << 3);
#pragma unroll
    for (int kk = 0; kk < 16; ++kk)
      qfr[kk] = *(const short8v*)(qrow + (kk << 4));
  }

  float16v acc[8];
#pragma unroll
  for (int dt = 0; dt < 8; ++dt) acc[dt] = (float16v)(0.0f);
  float lsum = 0.f;

  const int ksw = ((c32 & 7) << 3) | (((c32 >> 3) & 3) << 6);
  const int vsw = (c32 >> 3) & 3;
  const int voff0 = (hi ^ vsw) << 3;
  const int voff1 = ((2 + hi) ^ vsw) << 3;

  const int nit = kchunk >> 5;
  for (int it = 0; it < nit; ++it) {
    asm volatile("s_waitcnt vmcnt(0)" ::: "memory");
    __syncthreads();
    if (it + 1 < nit) {
      kptr += 32 * 256;
      vptr += 32;
      FSTAGE((it + 1) & 1)
    }
    const ushort* Kp = Kbuf[it & 1];
    const ushort* Vp = Vbuf[it & 1];

    // ---- S[key][q] = K @ Q^T (32x32, k=256) ----
    float16v s = (float16v)(0.0f);
    __builtin_amdgcn_s_setprio(1);
#pragma unroll
    for (int kk = 0; kk < 16; ++kk) {
      short8v kf = *(const short8v*)&Kp[(c32 << 8) + (((kk << 4) + (hi << 3)) ^ ksw)];
      s = __builtin_amdgcn_mfma_f32_32x32x16_bf16(kf, qfr[kk], s, 0, 0, 0);
    }
    __builtin_amdgcn_s_setprio(0);

    // ---- p = exp2(s), deferred l, P->A-frag via cvt_pk + permlane32_swap ----
    float p[16];
#pragma unroll
    for (int r = 0; r < 16; ++r) p[r] = exp2f(s[r]);
    {
      float t0 = (p[0] + p[1]) + (p[2] + p[3]);
      float t1 = (p[4] + p[5]) + (p[6] + p[7]);
      float t2 = (p[8] + p[9]) + (p[10] + p[11]);
      float t3 = (p[12] + p[13]) + (p[14] + p[15]);
      lsum += (t0 + t1) + (t2 + t3);
    }
    unsigned u0, u1, u2, u3, u4, u5, u6, u7;
    asm("v_cvt_pk_bf16_f32 %0, %1, %2" : "=v"(u0) : "v"(p[0]),  "v"(p[1]));
    asm("v_cvt_pk_bf16_f32 %0, %1, %2" : "=v"(u1) : "v"(p[2]),  "v"(p[3]));
    asm("v_cvt_pk_bf16_f32 %0, %1, %2" : "=v"(u2) : "v"(p[4]),  "v"(p[5]));
    asm("v_cvt_pk_bf16_f32 %0, %1, %2" : "=v"(u3) : "v"(p[6]),  "v"(p[7]));
    asm("v_cvt_pk_bf16_f32 %0, %1, %2" : "=v"(u4) : "v"(p[8]),  "v"(p[9]));
    asm("v_cvt_pk_bf16_f32 %0, %1, %2" : "=v"(u5) : "v"(p[10]), "v"(p[11]));
    asm("v_cvt_pk_bf16_f32 %0, %1, %2" : "=v"(u6) : "v"(p[12]), "v"(p[13]));
    asm("v_cvt_pk_bf16_f32 %0, %1, %2" : "=v"(u7) : "v"(p[14]), "v"(p[15]));
    asm volatile("v_permlane32_swap_b32 %0, %1" : "+v"(u0), "+v"(u2));
    asm volatile("v_permlane32_swap_b32 %0, %1" : "+v"(u1), "+v"(u3));
    asm volatile("v_permlane32_swap_b32 %0, %1" : "+v"(u4), "+v"(u6));
    asm volatile("v_permlane32_swap_b32 %0, %1" : "+v"(u5), "+v"(u7));
    union { unsigned uu[4]; short8v v; } P0, P1;
    P0.uu[0] = u0; P0.uu[1] = u1; P0.uu[2] = u2; P0.uu[3] = u3;  // keys 0..15
    P1.uu[0] = u4; P1.uu[1] = u5; P1.uu[2] = u6; P1.uu[3] = u7;  // keys 16..31

    // ---- O[q][d] += P @ V (8 x 32x32x16, 2 k-halves) ----
    __builtin_amdgcn_s_setprio(1);
#pragma unroll
    for (int dt = 0; dt < 8; ++dt) {
      const int drow = (dt << 5) + c32;
      short8v vf0 = *(const short8v*)&Vp[(drow << 5) + voff0];
      short8v vf1 = *(const short8v*)&Vp[(drow << 5) + voff1];
      acc[dt] = __builtin_amdgcn_mfma_f32_32x32x16_bf16(P0.v, vf0, acc[dt], 0, 0, 0);
      acc[dt] = __builtin_amdgcn_mfma_f32_32x32x16_bf16(P1.v, vf1, acc[dt], 0, 0, 0);
    }
    __builtin_amdgcn_s_setprio(0);
  }
#undef FSTAGE

  float lt = lsum + __shfl_xor(lsum, 32);
  if (hi == 0) ml[(size_t)ks * NN + q0 + wv * 32 + c32] = lt;
  ushort* op = opb + (size_t)ks * (NN * DD);
#pragma unroll
  for (int dt = 0; dt < 8; ++dt)
#pragma unroll
    for (int r = 0; r < 16; ++r) {
      const int qrow = q0 + wv * 32 + (r & 3) + ((r >> 2) << 3) + (hi << 2);
      op[(size_t)qrow * DD + (dt << 5) + c32] = f2bf(acc[dt][r]);
    }
}

// ---------------- FUSED epilogue: merge + Wo-proj + LN2 + FFN1(relu) + FFN2 + LN3 ----------------
__global__ __launch_bounds__(512, 4) void epilogue_kernel(
    const ushort* __restrict__ opb, const float* __restrict__ ml,
    const ushort* __restrict__ h1b,
    const ushort* __restrict__ WoT, const float* __restrict__ bo,
    const float* __restrict__ g2, const float* __restrict__ be2,
    const ushort* __restrict__ W1T, const float* __restrict__ b1,
    const ushort* __restrict__ W2T, const float* __restrict__ b2,
    const float* __restrict__ g3, const float* __restrict__ be3,
    float* __restrict__ out, int ksn)
{
  __shared__ float  yL[32 * 256];    // 32 KB: y, then h2 (f32) after LN2
  __shared__ ushort h2bL[32 * 256];  // 16 KB swizzled
  __shared__ ushort tL[32 * 512];    // 32 KB swizzled; hgL aliases first 16 KB; y2L f32 later

  ushort* hgL = tL;                  // [32][256] bf16, slot-swizzled

  const int tid = threadIdx.x;
  const int c32 = tid & 31, hi = (tid >> 5) & 1;
  const int wv = tid >> 6;           // 0..7
  const int lane = tid & 63;
  const int m0 = blockIdx.x * 32;
  const int n0 = wv << 5;            // 32-col group for S1/S5
  const int col = n0 + c32;

  // ---- S0: merge partials -> hgL (bf16, swizzled) ----
  {
    const int row = tid >> 4;               // 0..31
    const int cseg = (tid & 15) << 4;       // 16 cols
    const int growp = m0 + row;
    float L = 0.f;
    for (int i = 0; i < ksn; ++i) L += ml[(size_t)i * NN + growp];
    const float invl = 1.0f / L;
    float num[16];
#pragma unroll
    for (int j = 0; j < 16; ++j) num[j] = 0.f;
    for (int i = 0; i < ksn; ++i) {
      const ushort* src = opb + (size_t)i * ((size_t)NN * DD) + (size_t)growp * DD + cseg;
      short8v v0 = *(const short8v*)src;
      short8v v1 = *(const short8v*)(src + 8);
#pragma unroll
      for (int j = 0; j < 8; ++j) {
        num[j]     += b2f((ushort)v0[j]);
        num[8 + j] += b2f((ushort)v1[j]);
      }
    }
    const int swz = (row & 7) ^ (((row >> 3) & 3) << 3);
    const int sl0 = (cseg >> 3);
    union { ushort us[8]; short8v v; } o0, o1;
#pragma unroll
    for (int j = 0; j < 8; ++j) {
      o0.us[j] = f2bf(num[j] * invl);
      o1.us[j] = f2bf(num[8 + j] * invl);
    }
    *(short8v*)&hgL[(row << 8) + ((sl0 ^ swz) << 3)] = o0.v;
    *(short8v*)&hgL[(row << 8) + (((sl0 + 1) ^ swz) << 3)] = o1.v;
  }
  __syncthreads();

  // ---- S1: Wo GEMM C[32][256] (A from hgL) ----
  float16v acc = (float16v)(0.0f);
  {
    const int aswz = (c32 & 7) ^ (((c32 >> 3) & 3) << 3);
#pragma unroll
    for (int k0 = 0; k0 < 256; k0 += 16) {
      const int sA = (k0 >> 3) + hi;
      short8v af = *(const short8v*)&hgL[(c32 << 8) + ((sA ^ aswz) << 3)];
      short8v bf = *(const short8v*)&WoT[(size_t)col * 256 + k0 + (hi << 3)];
      acc = __builtin_amdgcn_mfma_f32_32x32x16_bf16(af, bf, acc, 0, 0, 0);
    }
  }
  // ---- S2: y = C + bo + h1 (bf16) -> yL ----
  {
    const float bov = bo[col];
#pragma unroll
    for (int r = 0; r < 16; ++r) {
      const int row = (r & 3) + ((r >> 2) << 3) + (hi << 2);
      yL[(row << 8) + col] = acc[r] + bov + b2f(h1b[(size_t)(m0 + row) * 256 + col]);
    }
  }
  __syncthreads();
  // ---- S3: LN2 ----
#pragma unroll
  for (int rr = 0; rr < 4; ++rr) {
    const int row = (wv << 2) + rr;
    const int c4 = lane << 2;
    float4 v = *(const float4*)&yL[(row << 8) + c4];
    float s1 = (v.x + v.y) + (v.z + v.w);
    float s2 = (v.x * v.x + v.y * v.y) + (v.z * v.z + v.w * v.w);
#pragma unroll
    for (int m = 1; m <= 32; m <<= 1) { s1 += __shfl_xor(s1, m); s2 += __shfl_xor(s2, m); }
    float mu = s1 * (1.0f / 256.0f);
    float var = s2 * (1.0f / 256.0f) - mu * mu;
    float inv = rsqrtf(fmaxf(var, 0.0f) + 1e-5f);
    float4 g4 = *(const float4*)&g2[c4];
    float4 b4 = *(const float4*)&be2[c4];
    float o0 = (v.x - mu) * inv * g4.x + b4.x;
    float o1 = (v.y - mu) * inv * g4.y + b4.y;
    float o2 = (v.z - mu) * inv * g4.z + b4.z;
    float o3 = (v.w - mu) * inv * g4.w + b4.w;
    *(float4*)&yL[(row << 8) + c4] = make_float4(o0, o1, o2, o3);
    const int psl = (c4 >> 3) ^ (row & 7);
    ushort4 ob; ob.x = f2bf(o0); ob.y = f2bf(o1); ob.z = f2bf(o2); ob.w = f2bf(o3);
    *(ushort4*)&h2bL[(row << 8) + (psl << 3) + (c4 & 7)] = ob;
  }
  __syncthreads();
  // ---- S4: FFN1 (relu) ----
  {
    float16v a1[2] = {(float16v)(0.0f), (float16v)(0.0f)};
    const int f0 = wv << 6;
#pragma unroll
    for (int k0 = 0; k0 < 256; k0 += 16) {
      const int s = (k0 >> 3) + hi;
      short8v af = *(const short8v*)&h2bL[(c32 << 8) + ((s ^ (c32 & 7)) << 3)];
#pragma unroll
      for (int nt = 0; nt < 2; ++nt) {
        short8v bf = *(const short8v*)&W1T[(size_t)(f0 + (nt << 5) + c32) * 256 + k0 + (hi << 3)];
        a1[nt] = __builtin_amdgcn_mfma_f32_32x32x16_bf16(af, bf, a1[nt], 0, 0, 0);
      }
    }
#pragma unroll
    for (int nt = 0; nt < 2; ++nt) {
      const int col1 = f0 + (nt << 5) + c32;
      const float b1v = b1[col1];
#pragma unroll
      for (int r = 0; r < 16; ++r) {
        const int row = (r & 3) + ((r >> 2) << 3) + (hi << 2);
        float v = fmaxf(a1[nt][r] + b1v, 0.0f);
        const int psl = (col1 >> 3) ^ (row & 7);
        tL[(row << 9) + (psl << 3) + (col1 & 7)] = f2bf(v);
      }
    }
  }
  __syncthreads();
  // ---- S5: FFN2 (+ h2 residual) ----
  float16v a2 = (float16v)(0.0f);
#pragma unroll
  for (int k0 = 0; k0 < 512; k0 += 16) {
    const int s = (k0 >> 3) + hi;
    short8v af = *(const short8v*)&tL[(c32 << 9) + ((s ^ (c32 & 7)) << 3)];
    short8v bf = *(const short8v*)&W2T[(size_t)col * 512 + k0 + (hi << 3)];
    a2 = __builtin_amdgcn_mfma_f32_32x32x16_bf16(af, bf, a2, 0, 0, 0);
  }
  {
    const float b2v = b2[col];
#pragma unroll
    for (int r = 0; r < 16; ++r) {
      const int row = (r & 3) + ((r >> 2) << 3) + (hi << 2);
      a2[r] += b2v + yL[(row << 8) + col];   // + h2 residual
    }
  }
  __syncthreads();                            // all tL reads complete
  {
    float* y2L = (float*)tL;
#pragma unroll
    for (int r = 0; r < 16; ++r) {
      const int row = (r & 3) + ((r >> 2) << 3) + (hi << 2);
      y2L[(row << 8) + col] = a2[r];
    }
  }
  __syncthreads();
  // ---- S6: LN3 -> out ----
  {
    const float* y2L = (const float*)tL;
#pragma unroll
    for (int rr = 0; rr < 4; ++rr) {
      const int row = (wv << 2) + rr;
      const int c4 = lane << 2;
      float4 v = *(const float4*)&y2L[(row << 8) + c4];
      float s1 = (v.x + v.y) + (v.z + v.w);
      float s2 = (v.x * v.x + v.y * v.y) + (v.z * v.z + v.w * v.w);
#pragma unroll
      for (int m = 1; m <= 32; m <<= 1) { s1 += __shfl_xor(s1, m); s2 += __shfl_xor(s2, m); }
      float mu = s1 * (1.0f / 256.0f);
      float var = s2 * (1.0f / 256.0f) - mu * mu;
      float inv = rsqrtf(fmaxf(var, 0.0f) + 1e-5f);
      float4 g4 = *(const float4*)&g3[c4];
      float4 b4 = *(const float4*)&be3[c4];
      float4 o;
      o.x = (v.x - mu) * inv * g4.x + b4.x;
      o.y = (v.y - mu) * inv * g4.y + b4.y;
      o.z = (v.z - mu) * inv * g4.z + b4.z;
      o.w = (v.w - mu) * inv * g4.w + b4.w;
      *(float4*)&out[(size_t)(m0 + row) * 256 + c4] = o;
    }
  }
}

extern "C" void kernel_launch(void* const* d_in, const int* in_sizes, int n_in,
                              void* d_out, int out_size, void* d_ws, size_t ws_size,
                              hipStream_t stream) {
  (void)in_sizes; (void)n_in; (void)out_size;
  const float* h     = (const float*)d_in[0];
  const int*   ei    = (const int*)  d_in[1];
  const float* W_gcn = (const float*)d_in[2];
  const float* b_gcn = (const float*)d_in[3];
  const float* Wq    = (const float*)d_in[4];
  const float* bq    = (const float*)d_in[5];
  const float* Wk    = (const float*)d_in[6];
  const float* bk    = (const float*)d_in[7];
  const float* Wv    = (const float*)d_in[8];
  const float* bv    = (const float*)d_in[9];
  const float* Wo    = (const float*)d_in[10];
  const float* bo    = (const float*)d_in[11];
  const float* RF    = (const float*)d_in[12];
  const float* g1    = (const float*)d_in[13];
  const float* be1   = (const float*)d_in[14];
  const float* g2    = (const float*)d_in[15];
  const float* be2   = (const float*)d_in[16];
  const float* g3    = (const float*)d_in[17];
  const float* be3   = (const float*)d_in[18];
  const float* W1    = (const float*)d_in[19];
  const float* b1    = (const float*)d_in[20];
  const float* W2    = (const float*)d_in[21];
  const float* b2    = (const float*)d_in[22];
  float* out = (float*)d_out;

  const size_t M2 = (size_t)NN * DD;
  const int ksn = (ws_size >= (size_t)64 * 1024 * 1024) ? 8 : 4;
  const int kchunk = NN / ksn;

  char* base = (char*)d_ws;
  ushort* hbX  = (ushort*)base; base += M2 * 2;
  ushort* h1bX = (ushort*)base; base += M2 * 2;
  ushort* qb   = (ushort*)base; base += M2 * 2;
  ushort* kb   = (ushort*)base; base += M2 * 2;
  ushort* vbT  = (ushort*)base; base += M2 * 2;
  ushort* opb  = (ushort*)base;
  float*  R    = (float*)opb;   base += (size_t)ksn * M2 * 2;
  float*  mlf  = (float*)base;  base += (size_t)8 * NN * 4;
  ushort* WgcnT = (ushort*)base; base += DD * DD * 2;
  ushort* Wcat  = (ushort*)base; base += (size_t)768 * DD * 2;
  ushort* WoT   = (ushort*)base; base += DD * DD * 2;
  ushort* W1T   = (ushort*)base; base += FF * DD * 2;
  ushort* W2T   = (ushort*)base; base += DD * FF * 2;
  ushort* RFb   = (ushort*)base; base += DD * DD * 2;
  ushort* Wqkb  = (ushort*)base; base += (size_t)2 * DD * DD * 2;
  float*  bcat  = (float*)base;  base += 768 * 4;
  float*  dinv  = (float*)base;  base += NN * 4;
  int* degi    = (int*)base; base += NN * 4;
  int* cursor  = (int*)base; base += NN * 4;
  int* csr_off = (int*)base; base += (NN + 4) * 4;
  int* csr_src = (int*)base; base += EE * 4;

  // aliases
  ushort* xwb = (ushort*)R;        // bf16 xw, pre-flash (R region is opb during flash)

  // zero degi + cursor (contiguous)
  hipMemsetAsync(degi, 0, (size_t)2 * NN * sizeof(int), stream);

  // fused precompute (+ bias folds + edge count)
  prep_kernel<<<P1B + 2 + 1024, 256, 0, stream>>>(
      h, W_gcn, Wv, Wo, W1, W2, bv, Wq, Wk, bq, bk, RF, ei,
      hbX, WgcnT, Wcat, WoT, W1T, W2T, RFb, Wqkb, bcat, degi);

  // dual GEMM: xw = hb @ WgcnT  AND  Wcat[q|k] = RFb @ Wqkb
  gemm_bf16_kernel<6, false><<<dim3(8, 132), 512, 0, stream>>>(
      hbX, WgcnT, nullptr, xwb, RFb, Wqkb, Wcat, NN, DD, DD);

  // CSR
  scan_kernel<<<1, 1024, 0, stream>>>(degi, csr_off, dinv);
  fill_kernel<<<EE / 256, 256, 0, stream>>>(ei, csr_off, cursor, csr_src);

  // local GCN + LN1 (bf16 out)
  gcn_gather_ln_kernel<<<NN / 4, 256, 0, stream>>>(xwb, h, dinv, csr_off, csr_src, b_gcn, g1, be1, h1bX);
  // fused q/k/v projections (single GEMM, routed epilogue)
  gemm_bf16_kernel<3, false><<<dim3(768 / 64, NN / 64), 512, 0, stream>>>(
      h1bX, Wcat, bcat, qb, kb, vbT, nullptr, NN, 768, DD);
  // attention (128 q-rows/block, 2 blocks/CU)
  flash_mfma_kernel<<<(NN / 128) * ksn, 256, 0, stream>>>(qb, kb, vbT, opb, mlf, ksn, kchunk);
  // fused merge + Wo + LN2 + FFN + LN3 -> out
  epilogue_kernel<<<NN / 32, 512, 0, stream>>>(
      opb, mlf, h1bX, WoT, bo, g2, be2, W1T, b1, W2T, b2, g3, be3, out, ksn);
}